// Round 7
// baseline (547.070 us; speedup 1.0000x reference)
//
#include <hip/hip_runtime.h>

#define N_ATOMS   100000
#define N_BONDS   220000
#define N_MESS    20000
#define N_MSG     (N_MESS + N_BONDS)        // 240000
#define ATOM_FDIM 35
#define BOND_FDIM 5
#define BOND_IN   (ATOM_FDIM + BOND_FDIM)   // 40
#define H         128
#define MAX_NB    10
#define NB_PAD    12                        // padded stride for 16B-aligned idx loads
#define DEPTH     6
#define KO        (ATOM_FDIM + H)           // 163
#define KC        192                       // padded K for both GEMMs
#define QLDS_STR  144                       // byte-stage stride (16-mult, breaks bank alias)
#define SC_BIAS   887u                      // scf = asf((code+887)<<20), 3 mantissa bits

typedef __attribute__((ext_vector_type(8))) short short8;   // 8 bf16 (4 VGPRs)
typedef __attribute__((ext_vector_type(4))) float f32x4;    // MFMA C/D frag

static __device__ __forceinline__ float asf(unsigned int u) {
    union { unsigned int i; float f; } v; v.i = u; return v.f;
}

static __device__ __forceinline__ unsigned short f2bf(float f) {
    union { float f; unsigned int i; } v; v.f = f;
    unsigned int x = v.i;
    return (unsigned short)((x + 0x7FFFu + ((x >> 16) & 1u)) >> 16);
}

// byte b of u32 -> float; clang folds to v_cvt_f32_ubyte{0..3}
static __device__ __forceinline__ float ub2f(unsigned int v, int b) {
    return (float)((v >> (b * 8)) & 0xffu);
}

// scale code from row max-abs: smallest code with scf >= mx/127 (round UP)
static __device__ __forceinline__ int sc_code(float mx) {
    float t = mx * (1.f / 127.f);
    int code = (int)((__float_as_uint(t) + 0xFFFFFu) >> 20) - (int)SC_BIAS;
    return code < 1 ? 1 : (code > 255 ? 255 : code);
}
static __device__ __forceinline__ float sc_val(int code) {
    return asf(((unsigned)code + SC_BIAS) << 20);
}

// ---------------------------------------------------------------------------
// prep (fused): fbonds->bf16, weight transposes, graph padding, out zeroing,
// PLUS qtree quantization blocks, PLUS per-molecule inverse-count table.
// ---------------------------------------------------------------------------
#define PTa (N_BONDS * BOND_IN)             // fbc
#define PTb (PTa + H * KC)                  // WT
#define PTc (PTb + H * KC)                  // WoT
#define PTd (PTc + N_BONDS * MAX_NB)        // bgraphP
#define PTe (PTd + N_ATOMS * MAX_NB)        // agraphP
#define NB_QT (N_MESS / 4)                  // 5000 qtree blocks (4 rows each)

__global__ __launch_bounds__(256) void prep(
    const float* __restrict__ fbonds,
    const float* __restrict__ Wi, const float* __restrict__ Wh,
    const float* __restrict__ Wo,
    const int* __restrict__ bgraph, const int* __restrict__ agraph,
    const float* __restrict__ tree, const int* __restrict__ mol_ids,
    ushort* __restrict__ fbc, ushort* __restrict__ WT,
    ushort* __restrict__ WoT,
    int* __restrict__ bgP, int* __restrict__ agP,
    ushort* __restrict__ qA, ushort* __restrict__ qB,
    unsigned char* __restrict__ sA, unsigned char* __restrict__ sB,
    float* __restrict__ icnt,
    float* __restrict__ out, int n_out, int nbElem, int n_mols)
{
    int blk = blockIdx.x;
    int tid = threadIdx.x;

    if (blk < nbElem) {                    // ---- elementwise conversions ----
        int i = blk * 256 + tid;
        if (i < PTa) {
            fbc[i] = f2bf(fbonds[i]);
        } else if (i < PTb) {
            int j = i - PTa;
            int n = j / KC, k = j - n * KC;
            float v = (k < BOND_IN) ? Wi[k * H + n]
                    : (k < BOND_IN + H) ? Wh[(k - BOND_IN) * H + n] : 0.f;
            WT[j] = f2bf(v);
        } else if (i < PTc) {
            int j = i - PTb;
            int n = j / KC, k = j - n * KC;
            float v = (k < H) ? Wo[(ATOM_FDIM + k) * H + n]
                    : (k < KO) ? Wo[(k - H) * H + n] : 0.f;
            WoT[j] = f2bf(v);
        } else if (i < PTd) {
            int j = i - PTc;
            int b = j / MAX_NB, n = j - b * MAX_NB;
            bgP[b * NB_PAD + n] = bgraph[j];
        } else if (i < PTe) {
            int j = i - PTd;
            int a = j / MAX_NB, n = j - a * MAX_NB;
            agP[a * NB_PAD + n] = agraph[j];
        } else {
            int j = i - PTe;
            if (j < n_out) out[j] = 0.f;
        }
    } else if (blk < nbElem + NB_QT) {     // ---- qtree: 4 rows per block ----
        int row = (blk - nbElem) * 4 + (tid >> 6);
        int lane = tid & 63;
        float2 v = *(const float2*)&tree[(size_t)row * H + lane * 2];
        float mx = fmaxf(fabsf(v.x), fabsf(v.y));
        #pragma unroll
        for (int d = 1; d <= 32; d <<= 1)
            mx = fmaxf(mx, __shfl_xor(mx, d));
        int code = sc_code(mx);
        float inv = __builtin_amdgcn_rcpf(sc_val(code));
        int u0 = __float2int_rn(v.x * inv) + 128;
        int u1 = __float2int_rn(v.y * inv) + 128;
        u0 = u0 < 0 ? 0 : (u0 > 255 ? 255 : u0);
        u1 = u1 < 0 ? 0 : (u1 > 255 ? 255 : u1);
        unsigned short pk = (unsigned short)(u0 | (u1 << 8));
        qA[(size_t)row * 64 + lane] = pk;
        qB[(size_t)row * 64 + lane] = pk;
        if (lane == 0) { sA[row] = (unsigned char)code; sB[row] = (unsigned char)code; }
    } else {                               // ---- inverse molecule counts ----
        int m = (blk - nbElem - NB_QT) * 256 + tid;
        if (m < n_mols) {
            int lo = 0, hi = N_ATOMS;
            while (lo < hi) { int mid = (lo + hi) >> 1; if (mol_ids[mid] < m) lo = mid + 1; else hi = mid; }
            int start = lo;
            hi = N_ATOMS;
            while (lo < hi) { int mid = (lo + hi) >> 1; if (mol_ids[mid] < m + 1) lo = mid + 1; else hi = mid; }
            icnt[m] = 1.f / fmaxf((float)(lo - start), 1.f);
        }
    }
}

// ---------------------------------------------------------------------------
// decode10: sum 10 bias-128 u8 row-slices with per-row e8 code scales.
// ---------------------------------------------------------------------------
static __device__ __forceinline__ uint4 decode10(
    const uint2* d, const unsigned char* k)
{
    float s0=0.f,s1=0.f,s2=0.f,s3=0.f,s4=0.f,s5=0.f,s6=0.f,s7=0.f;
    float ssum = 0.f;
    #pragma unroll
    for (int n = 0; n < MAX_NB; n++) {
        float sc = sc_val((int)k[n]); ssum += sc;
        s0 += sc * ub2f(d[n].x, 0); s1 += sc * ub2f(d[n].x, 1);
        s2 += sc * ub2f(d[n].x, 2); s3 += sc * ub2f(d[n].x, 3);
        s4 += sc * ub2f(d[n].y, 0); s5 += sc * ub2f(d[n].y, 1);
        s6 += sc * ub2f(d[n].y, 2); s7 += sc * ub2f(d[n].y, 3);
    }
    s0 = fmaf(-128.f, ssum, s0); s1 = fmaf(-128.f, ssum, s1);
    s2 = fmaf(-128.f, ssum, s2); s3 = fmaf(-128.f, ssum, s3);
    s4 = fmaf(-128.f, ssum, s4); s5 = fmaf(-128.f, ssum, s5);
    s6 = fmaf(-128.f, ssum, s6); s7 = fmaf(-128.f, ssum, s7);
    uint4 pk;
    asm("v_cvt_pk_bf16_f32 %0, %1, %2" : "=v"(pk.x) : "v"(s0), "v"(s1));
    asm("v_cvt_pk_bf16_f32 %0, %1, %2" : "=v"(pk.y) : "v"(s2), "v"(s3));
    asm("v_cvt_pk_bf16_f32 %0, %1, %2" : "=v"(pk.z) : "v"(s4), "v"(s5));
    asm("v_cvt_pk_bf16_f32 %0, %1, %2" : "=v"(pk.w) : "v"(s6), "v"(s7));
    return pk;
}

// ---------------------------------------------------------------------------
// gather2_u8c: BOTH row-groups' loads issued before any decode (2x MLP:
// ~40 data lines in flight per wave instead of ~20 at VGPR=36).
// ---------------------------------------------------------------------------
static __device__ __forceinline__ void gather2_u8c(
    const uint2* __restrict__ msgq, const unsigned char* __restrict__ scl,
    const int* __restrict__ g0, const int* __restrict__ g1, int c16,
    uint4* pk0, uint4* pk1)
{
    uint4 x0 = *(const uint4*)g0; uint4 x1 = *(const uint4*)(g0 + 4);
    uint2 x2 = *(const uint2*)(g0 + 8);
    uint4 y0 = *(const uint4*)g1; uint4 y1 = *(const uint4*)(g1 + 4);
    uint2 y2 = *(const uint2*)(g1 + 8);
    int ia[MAX_NB] = {(int)x0.x,(int)x0.y,(int)x0.z,(int)x0.w,
                      (int)x1.x,(int)x1.y,(int)x1.z,(int)x1.w,(int)x2.x,(int)x2.y};
    int ib[MAX_NB] = {(int)y0.x,(int)y0.y,(int)y0.z,(int)y0.w,
                      (int)y1.x,(int)y1.y,(int)y1.z,(int)y1.w,(int)y2.x,(int)y2.y};
    uint2 da[MAX_NB], db[MAX_NB];
    unsigned char ka[MAX_NB], kb[MAX_NB];
    #pragma unroll
    for (int n = 0; n < MAX_NB; n++) da[n] = msgq[(size_t)ia[n] * 16 + c16];
    #pragma unroll
    for (int n = 0; n < MAX_NB; n++) db[n] = msgq[(size_t)ib[n] * 16 + c16];
    #pragma unroll
    for (int n = 0; n < MAX_NB; n++) ka[n] = scl[ia[n]];
    #pragma unroll
    for (int n = 0; n < MAX_NB; n++) kb[n] = scl[ib[n]];
    *pk0 = decode10(da, ka);
    *pk1 = decode10(db, kb);
}

// ---------------------------------------------------------------------------
// u8_epilogue: relu + per-row bias-128 u8 quantize with 1-byte scale code.
// qlds ALIASES Xlds (all Xlds reads retired at the first barrier here).
// ---------------------------------------------------------------------------
static __device__ __forceinline__ void u8_epilogue(
    f32x4 c00, f32x4 c01, f32x4 c10, f32x4 c11,
    int tid, int row_base,
    float* rmx /*32*4*/, float* qp /*32*/, char* qlds,
    uint4* __restrict__ gq4, unsigned char* __restrict__ scout)
{
    int lane = tid & 63, wv = tid >> 6;
    int m_lane = lane & 15, quad = lane >> 4;
    int n0 = wv * 32;

    float v00[4], v01[4], v10[4], v11[4];
    #pragma unroll
    for (int r = 0; r < 4; r++) {
        v00[r] = fmaxf(c00[r], 0.f); v01[r] = fmaxf(c01[r], 0.f);
        v10[r] = fmaxf(c10[r], 0.f); v11[r] = fmaxf(c11[r], 0.f);
    }
    #pragma unroll
    for (int r = 0; r < 4; r++) {
        float mx0 = fmaxf(v00[r], v01[r]);
        float mx1 = fmaxf(v10[r], v11[r]);
        #pragma unroll
        for (int d = 1; d <= 8; d <<= 1) {
            mx0 = fmaxf(mx0, __shfl_xor(mx0, d));
            mx1 = fmaxf(mx1, __shfl_xor(mx1, d));
        }
        if (m_lane == 0) {
            rmx[(quad * 4 + r) * 4 + wv]      = mx0;
            rmx[(quad * 4 + r + 16) * 4 + wv] = mx1;
        }
    }
    __syncthreads();                       // retires all Xlds reads too
    if (tid < 32) {
        float mx = fmaxf(fmaxf(rmx[tid * 4], rmx[tid * 4 + 1]),
                         fmaxf(rmx[tid * 4 + 2], rmx[tid * 4 + 3]));
        int code = sc_code(mx);
        qp[tid] = __builtin_amdgcn_rcpf(sc_val(code));
        scout[row_base + tid] = (unsigned char)code;
    }
    __syncthreads();
    #pragma unroll
    for (int r = 0; r < 4; r++) {
        int r0 = quad * 4 + r, r1 = r0 + 16;
        float i0 = qp[r0], i1 = qp[r1];
        // post-relu x >= 0 -> u in [128,255]; clamp top only
        int u00 = __float2int_rn(v00[r] * i0) + 128;
        int u01 = __float2int_rn(v01[r] * i0) + 128;
        int u10 = __float2int_rn(v10[r] * i1) + 128;
        int u11 = __float2int_rn(v11[r] * i1) + 128;
        qlds[r0 * QLDS_STR + n0 + m_lane]      = (char)(u00 > 255 ? 255 : u00);
        qlds[r0 * QLDS_STR + n0 + 16 + m_lane] = (char)(u01 > 255 ? 255 : u01);
        qlds[r1 * QLDS_STR + n0 + m_lane]      = (char)(u10 > 255 ? 255 : u10);
        qlds[r1 * QLDS_STR + n0 + 16 + m_lane] = (char)(u11 > 255 ? 255 : u11);
    }
    __syncthreads();
    int row = tid >> 3, seg = tid & 7;        // 32 rows x 8 uint4
    uint4 w = *(const uint4*)(qlds + row * QLDS_STR + seg * 16);
    gq4[(size_t)(row_base + row) * 8 + seg] = w;
}

// ---------------------------------------------------------------------------
// binput0 (MFMA): graph0 = relu(fbonds @ W_i) -> u8 rows. K cut to 64.
// ---------------------------------------------------------------------------
__global__ __launch_bounds__(256, 4) void binput0(
    const ushort* __restrict__ fbc, const ushort* __restrict__ WT,
    uint4* __restrict__ gq_out, unsigned char* __restrict__ sc_out)
{
    __shared__ __align__(16) ushort Xlds[32 * 25 * 8];
    __shared__ float rmx[32 * 4];
    __shared__ float qp[32];
    char* qlds = (char*)Xlds;              // aliased byte-stage

    int tid = threadIdx.x;
    int bond0 = blockIdx.x * 32;           // grid = 6875, exact
    int lane = tid & 63, wv = tid >> 6;

    if (tid < 160) {                       // b = tid/5, k8 = tid%5
        int b = tid / 5, k8 = tid - b * 5;
        *(short8*)&Xlds[(b * 25 + k8) * 8] =
            *(const short8*)&fbc[(size_t)bond0 * BOND_IN + tid * 8];
    }
    if (tid < 96) {                        // zero k in [40,64): cells 5..7
        int b = tid / 3, k8 = 5 + (tid - b * 3);
        *(float4*)&Xlds[(b * 25 + k8) * 8] = float4{0.f, 0.f, 0.f, 0.f};
    }
    __syncthreads();

    int n0 = wv * 32;
    int m_lane = lane & 15, quad = lane >> 4;
    f32x4 c00 = {0,0,0,0}, c01 = {0,0,0,0}, c10 = {0,0,0,0}, c11 = {0,0,0,0};

    #pragma unroll
    for (int s = 0; s < 2; s++) {          // K = 64 covers fb (k<40) + zeros
        short8 a0 = *(const short8*)&Xlds[((m_lane)      * 25 + s * 4 + quad) * 8];
        short8 a1 = *(const short8*)&Xlds[((16 + m_lane) * 25 + s * 4 + quad) * 8];
        short8 b0 = *(const short8*)&WT[(size_t)(n0 + m_lane)      * KC + s * 32 + quad * 8];
        short8 b1 = *(const short8*)&WT[(size_t)(n0 + 16 + m_lane) * KC + s * 32 + quad * 8];
        c00 = __builtin_amdgcn_mfma_f32_16x16x32_bf16(a0, b0, c00, 0, 0, 0);
        c01 = __builtin_amdgcn_mfma_f32_16x16x32_bf16(a0, b1, c01, 0, 0, 0);
        c10 = __builtin_amdgcn_mfma_f32_16x16x32_bf16(a1, b0, c10, 0, 0, 0);
        c11 = __builtin_amdgcn_mfma_f32_16x16x32_bf16(a1, b1, c11, 0, 0, 0);
    }

    u8_epilogue(c00, c01, c10, c11, tid, bond0, rmx, qp, qlds, gq_out, sc_out);
}

// ---------------------------------------------------------------------------
// mp_round (MFMA): graph_out[b] = relu([fb[b]|nei[b]|0] @ [Wi;Wh;0])
// Gather: deep-preload (both groups in flight) u8 rows + byte codes.
// ---------------------------------------------------------------------------
__global__ __launch_bounds__(256, 4) void mp_round(
    const uint2* __restrict__ msg_in, const unsigned char* __restrict__ sc_in,
    const ushort* __restrict__ fbc, const int* __restrict__ bgraphP,
    const ushort* __restrict__ WT,
    uint4* __restrict__ gq_out, unsigned char* __restrict__ sc_out)
{
    __shared__ __align__(16) ushort Xlds[32 * 25 * 8];   // 12800 B
    __shared__ float rmx[32 * 4];
    __shared__ float qp[32];
    char* qlds = (char*)Xlds;              // aliased byte-stage

    int tid = threadIdx.x;
    int bond0 = blockIdx.x * 32;           // grid = 6875, exact
    int lane = tid & 63, wv = tid >> 6;
    int q = lane >> 4, c16 = lane & 15;

    // stage fb tile (pre-converted bf16): 160 x 16 B copies
    if (tid < 160) {
        int b = tid / 5, k8 = tid - b * 5;
        *(short8*)&Xlds[(b * 25 + k8) * 8] =
            *(const short8*)&fbc[(size_t)bond0 * BOND_IN + tid * 8];
    }
    // zero pad k in [168,192): cells 21..23
    if (tid < 96) {
        int b = tid / 3, k8 = 21 + (tid - b * 3);
        *(float4*)&Xlds[(b * 25 + k8) * 8] = float4{0.f, 0.f, 0.f, 0.f};
    }
    // gather nei: rows b0 = wv+4q, b1 = wv+16+4q; lane sums elements
    // [c16*8, c16*8+8) of its row -> cell 5+c16.
    {
        int b0 = wv + 4 * q, b1 = wv + 16 + 4 * q;
        uint4 pk0, pk1;
        gather2_u8c(msg_in, sc_in,
                    bgraphP + (size_t)(bond0 + b0) * NB_PAD,
                    bgraphP + (size_t)(bond0 + b1) * NB_PAD, c16, &pk0, &pk1);
        *(uint4*)&Xlds[(b0 * 25 + 5 + c16) * 8] = pk0;
        *(uint4*)&Xlds[(b1 * 25 + 5 + c16) * 8] = pk1;
    }
    __syncthreads();

    int n0 = wv * 32;
    int m_lane = lane & 15, quad = lane >> 4;
    f32x4 c00 = {0,0,0,0}, c01 = {0,0,0,0}, c10 = {0,0,0,0}, c11 = {0,0,0,0};

    #pragma unroll
    for (int s = 0; s < KC / 32; s++) {
        short8 a0 = *(const short8*)&Xlds[((m_lane)      * 25 + s * 4 + quad) * 8];
        short8 a1 = *(const short8*)&Xlds[((16 + m_lane) * 25 + s * 4 + quad) * 8];
        short8 b0 = *(const short8*)&WT[(size_t)(n0 + m_lane)      * KC + s * 32 + quad * 8];
        short8 b1 = *(const short8*)&WT[(size_t)(n0 + 16 + m_lane) * KC + s * 32 + quad * 8];
        c00 = __builtin_amdgcn_mfma_f32_16x16x32_bf16(a0, b0, c00, 0, 0, 0);
        c01 = __builtin_amdgcn_mfma_f32_16x16x32_bf16(a0, b1, c01, 0, 0, 0);
        c10 = __builtin_amdgcn_mfma_f32_16x16x32_bf16(a1, b0, c10, 0, 0, 0);
        c11 = __builtin_amdgcn_mfma_f32_16x16x32_bf16(a1, b1, c11, 0, 0, 0);
    }

    u8_epilogue(c00, c01, c10, c11, tid, bond0, rmx, qp, qlds, gq_out, sc_out);
}

// ---------------------------------------------------------------------------
// atom_mfma: relu([nei|fatoms|0] @ WoT^T + b_o), per-molecule partial sums
// scaled by inv_count and atomicAdd'ed into out (pool_div folded in).
// ---------------------------------------------------------------------------
__global__ __launch_bounds__(256, 4) void atom_mfma(
    const float* __restrict__ fatoms, const uint2* __restrict__ msg,
    const unsigned char* __restrict__ scl,
    const int* __restrict__ agraphP, const ushort* __restrict__ WoT,
    const float* __restrict__ bo, const int* __restrict__ mol_ids,
    const float* __restrict__ icnt,
    float* __restrict__ out)
{
    __shared__ ushort Xlds[32 * 25 * 8];
    __shared__ float htile[32 * H];
    __shared__ int mlds[32];

    int tid = threadIdx.x;
    int a0 = blockIdx.x * 32;              // grid = 3125, exact
    int lane = tid & 63, wv = tid >> 6;
    int q = lane >> 4, c16 = lane & 15;

    // fatoms: k in [128,163)
    for (int i = tid; i < 32 * ATOM_FDIM; i += 256) {
        int b = i / ATOM_FDIM, t = i - b * ATOM_FDIM;
        int k = H + t;
        Xlds[(b * 25 + (k >> 3)) * 8 + (k & 7)] = f2bf(fatoms[(size_t)a0 * ATOM_FDIM + i]);
    }
    // zero k in [163,168)
    if (tid < 160) {
        int b = tid / 5, k = 163 + (tid - b * 5);
        Xlds[(b * 25 + (k >> 3)) * 8 + (k & 7)] = 0;
    }
    // zero cells 21..23 (k in [168,192))
    if (tid < 96) {
        int b = tid / 3, k8 = 21 + (tid - b * 3);
        *(float4*)&Xlds[(b * 25 + k8) * 8] = float4{0.f, 0.f, 0.f, 0.f};
    }
    if (tid < 32) mlds[tid] = mol_ids[a0 + tid];
    // gather nei: k in [0,128) -> cell c16
    {
        int b0 = wv + 4 * q, b1 = wv + 16 + 4 * q;
        uint4 pk0, pk1;
        gather2_u8c(msg, scl,
                    agraphP + (size_t)(a0 + b0) * NB_PAD,
                    agraphP + (size_t)(a0 + b1) * NB_PAD, c16, &pk0, &pk1);
        *(uint4*)&Xlds[(b0 * 25 + c16) * 8] = pk0;
        *(uint4*)&Xlds[(b1 * 25 + c16) * 8] = pk1;
    }
    __syncthreads();

    int n0 = wv * 32;
    int m_lane = lane & 15, quad = lane >> 4;
    float bias0 = bo[n0 + m_lane], bias1 = bo[n0 + 16 + m_lane];
    f32x4 c00 = {bias0, bias0, bias0, bias0};
    f32x4 c01 = {bias1, bias1, bias1, bias1};
    f32x4 c10 = {bias0, bias0, bias0, bias0};
    f32x4 c11 = {bias1, bias1, bias1, bias1};

    #pragma unroll
    for (int s = 0; s < KC / 32; s++) {
        short8 a0f = *(const short8*)&Xlds[((m_lane)      * 25 + s * 4 + quad) * 8];
        short8 a1f = *(const short8*)&Xlds[((16 + m_lane) * 25 + s * 4 + quad) * 8];
        short8 b0f = *(const short8*)&WoT[(size_t)(n0 + m_lane)      * KC + s * 32 + quad * 8];
        short8 b1f = *(const short8*)&WoT[(size_t)(n0 + 16 + m_lane) * KC + s * 32 + quad * 8];
        c00 = __builtin_amdgcn_mfma_f32_16x16x32_bf16(a0f, b0f, c00, 0, 0, 0);
        c01 = __builtin_amdgcn_mfma_f32_16x16x32_bf16(a0f, b1f, c01, 0, 0, 0);
        c10 = __builtin_amdgcn_mfma_f32_16x16x32_bf16(a1f, b0f, c10, 0, 0, 0);
        c11 = __builtin_amdgcn_mfma_f32_16x16x32_bf16(a1f, b1f, c11, 0, 0, 0);
    }

    #pragma unroll
    for (int r = 0; r < 4; r++) {
        int r0 = quad * 4 + r, r1 = r0 + 16;
        htile[r0 * H + n0 + m_lane]      = fmaxf(c00[r], 0.f);
        htile[r0 * H + n0 + 16 + m_lane] = fmaxf(c01[r], 0.f);
        htile[r1 * H + n0 + m_lane]      = fmaxf(c10[r], 0.f);
        htile[r1 * H + n0 + 16 + m_lane] = fmaxf(c11[r], 0.f);
    }
    __syncthreads();

    // segmented reduce; scale by inv_count at flush (pool_div folded in)
    if (tid < H) {
        int j = tid;
        float acc = 0.f;
        int cur = mlds[0];
        for (int r = 0; r < 32; r++) {
            int m = mlds[r];
            if (m != cur) {
                atomicAdd(&out[(size_t)cur * H + j], acc * icnt[cur]);
                acc = 0.f; cur = m;
            }
            acc += htile[r * H + j];
        }
        atomicAdd(&out[(size_t)cur * H + j], acc * icnt[cur]);
    }
}

// ---------------------------------------------------------------------------
extern "C" void kernel_launch(void* const* d_in, const int* in_sizes, int n_in,
                              void* d_out, int out_size, void* d_ws, size_t ws_size,
                              hipStream_t stream)
{
    const float* fatoms  = (const float*)d_in[0];
    const float* fbonds  = (const float*)d_in[1];
    const float* tree    = (const float*)d_in[2];
    const int*   agraph  = (const int*)d_in[3];
    const int*   bgraph  = (const int*)d_in[4];
    const int*   mol_ids = (const int*)d_in[5];
    const float* W_i = (const float*)d_in[7];
    const float* W_h = (const float*)d_in[8];
    const float* W_o = (const float*)d_in[9];
    const float* b_o = (const float*)d_in[10];
    float* out = (float*)d_out;

    // ws: mqA | mqB (u8 rows, 30.72 MB each) | scA | scB (u8 codes, 240 KB)
    //     | icnt (8 KB) | WT | WoT (48 KB each) | fbc (17.6 MB)
    //     | bgraphP (10.56 MB) | agraphP (4.8 MB)   ~95 MB
    uint2* mqA = (uint2*)d_ws;
    uint2* mqB = mqA + (size_t)N_MSG * 16;
    unsigned char* scA = (unsigned char*)(mqB + (size_t)N_MSG * 16);
    unsigned char* scB = scA + N_MSG;
    float* icnt = (float*)(scB + N_MSG);
    ushort* WT  = (ushort*)(icnt + 2048);
    ushort* WoT = WT + (size_t)H * KC;
    ushort* fbc = WoT + (size_t)H * KC;
    int* bgP = (int*)(fbc + (size_t)N_BONDS * BOND_IN);
    int* agP = bgP + (size_t)N_BONDS * NB_PAD;

    int n_mols = out_size / H;
    int nbElem = (PTe + out_size + 255) / 256;
    int nbTot = nbElem + NB_QT + (n_mols + 255) / 256;
    prep<<<nbTot, 256, 0, stream>>>(
        fbonds, W_i, W_h, W_o, bgraph, agraph, tree, mol_ids,
        fbc, WT, WoT, bgP, agP,
        (ushort*)mqA, (ushort*)mqB, scA, scB, icnt, out, out_size, nbElem, n_mols);

    binput0<<<N_BONDS / 32, 256, 0, stream>>>(fbc, WT,
        (uint4*)(mqA + (size_t)N_MESS * 16), scA + N_MESS);

    const uint2* tin = mqA; const unsigned char* sin = scA;
    uint2* tout = mqB; unsigned char* sout = scB;
    for (int r = 0; r < DEPTH - 1; r++) {
        mp_round<<<N_BONDS / 32, 256, 0, stream>>>(tin, sin, fbc, bgP, WT,
            (uint4*)(tout + (size_t)N_MESS * 16), sout + N_MESS);
        const uint2* t1 = tin; tin = tout; tout = (uint2*)t1;
        const unsigned char* t2 = sin; sin = sout; sout = (unsigned char*)t2;
    }
    // after 5 rounds the final message table is mqB (== tin)

    atom_mfma<<<N_ATOMS / 32, 256, 0, stream>>>(fatoms, tin, sin, agP, WoT, b_o,
                                                mol_ids, icnt, out);
}